// Round 2
// baseline (168.255 us; speedup 1.0000x reference)
//
#include <hip/hip_runtime.h>
#include <cstdio>

#define BB 2
#define TT 8
#define NNODE 5000
#define KK1 17
#define HH 4
#define CC 16
#define NT (BB*TT*NNODE)          // 80000 (b,t,n) nodes
#define NE2 (BB*7*NNODE*HH)       // 280000 threads for d_w

// ---- Kernel A1: g[m,h,i] = sum_j M[h][i][j] f[m,h,j]; s[m,h] = |g|^2
__global__ void __launch_bounds__(256) k_prep_g(
    const float* __restrict__ feat, const float* __restrict__ mm,
    float* __restrict__ g, float* __restrict__ s) {
  const int lane = threadIdx.x & 63;
  const int h = lane >> 4, i = lane & 15;
  const int wid = (blockIdx.x * blockDim.x + threadIdx.x) >> 6;
  const int nw = (gridDim.x * blockDim.x) >> 6;
  float Mrow[16];
#pragma unroll
  for (int j = 0; j < 16; ++j) Mrow[j] = mm[(h*16 + i)*16 + j];
  for (int m = wid; m < NT; m += nw) {
    const float4* fp = reinterpret_cast<const float4*>(feat + m*64 + h*16);
    float fv[16];
#pragma unroll
    for (int q = 0; q < 4; ++q) {
      float4 v = fp[q];
      fv[q*4+0] = v.x; fv[q*4+1] = v.y; fv[q*4+2] = v.z; fv[q*4+3] = v.w;
    }
    float acc = 0.f;
#pragma unroll
    for (int j = 0; j < 16; ++j) acc = fmaf(Mrow[j], fv[j], acc);
    g[m*64 + h*16 + i] = acc;
    float p = acc * acc;
    p += __shfl_xor(p, 1, 16);
    p += __shfl_xor(p, 2, 16);
    p += __shfl_xor(p, 4, 16);
    p += __shfl_xor(p, 8, 16);
    if (i == 0) s[m*4 + h] = p;
  }
}

// ---- Kernel A2: a8 = Q1[h] f (8 rows), b8 = Q2[h] f (8 rows)
__global__ void __launch_bounds__(256) k_prep_q(
    const float* __restrict__ feat, const float* __restrict__ q1, const float* __restrict__ q2,
    float* __restrict__ a8, float* __restrict__ b8) {
  const int lane = threadIdx.x & 63;
  const int h = lane >> 4, i = lane & 15;
  const int wid = (blockIdx.x * blockDim.x + threadIdx.x) >> 6;
  const int nw = (gridDim.x * blockDim.x) >> 6;
  const float* qsrc = (i < 8) ? (q1 + (h*8 + i)*16) : (q2 + (h*8 + (i - 8))*16);
  float Qrow[16];
#pragma unroll
  for (int j = 0; j < 16; ++j) Qrow[j] = qsrc[j];
  for (int m = wid; m < NT; m += nw) {
    const float4* fp = reinterpret_cast<const float4*>(feat + m*64 + h*16);
    float fv[16];
#pragma unroll
    for (int q = 0; q < 4; ++q) {
      float4 v = fp[q];
      fv[q*4+0] = v.x; fv[q*4+1] = v.y; fv[q*4+2] = v.z; fv[q*4+3] = v.w;
    }
    float acc = 0.f;
#pragma unroll
    for (int j = 0; j < 16; ++j) acc = fmaf(Qrow[j], fv[j], acc);
    if (i < 8) a8[m*32 + h*8 + i] = acc;
    else       b8[m*32 + h*8 + (i - 8)] = acc;
  }
}

// ---- Kernel B: deg[m,h] = sum_k valid * exp(-(s_i + s_j - 2 <g_i,g_j>))
__global__ void __launch_bounds__(256) k_deg(
    const float* __restrict__ g, const float* __restrict__ s,
    const int* __restrict__ nn, float* __restrict__ deg) {
  const int lane = threadIdx.x & 63;
  const int h = lane >> 4, k = lane & 15;
  const int m = (blockIdx.x * blockDim.x + threadIdx.x) >> 6;
  if (m >= NT) return;
  const int n = m % NNODE;
  const int btbase = m - n;   // bt*NNODE
  int jr = nn[n*KK1 + 1 + k];
  bool valid = jr >= 0;
  int j = valid ? jr : 0;
  const float4* pi = reinterpret_cast<const float4*>(g + m*64 + h*16);
  const float4* pj = reinterpret_cast<const float4*>(g + (btbase + j)*64 + h*16);
  float dot = 0.f;
#pragma unroll
  for (int q = 0; q < 4; ++q) {
    float4 a = pi[q], b = pj[q];
    dot = fmaf(a.x, b.x, dot); dot = fmaf(a.y, b.y, dot);
    dot = fmaf(a.z, b.z, dot); dot = fmaf(a.w, b.w, dot);
  }
  float e = s[m*4 + h] + s[(btbase + j)*4 + h] - 2.f*dot;
  float w = valid ? __expf(-e) : 0.f;
  float dsum = w;
  dsum += __shfl_xor(dsum, 1, 16);
  dsum += __shfl_xor(dsum, 2, 16);
  dsum += __shfl_xor(dsum, 4, 16);
  dsum += __shfl_xor(dsum, 8, 16);
  if (k == 0) deg[m*4 + h] = dsum;
}

// ---- Kernel C: u_w[m,k,h] = w * rsqrt(deg_i * deg_j)  (0 if invalid)
__global__ void __launch_bounds__(256) k_uw(
    const float* __restrict__ g, const float* __restrict__ s,
    const int* __restrict__ nn, const float* __restrict__ deg,
    float* __restrict__ uw) {
  const int lane = threadIdx.x & 63;
  const int h = lane >> 4, k = lane & 15;
  const int m = (blockIdx.x * blockDim.x + threadIdx.x) >> 6;
  if (m >= NT) return;
  const int n = m % NNODE;
  const int btbase = m - n;
  int jr = nn[n*KK1 + 1 + k];
  bool valid = jr >= 0;
  int j = valid ? jr : 0;
  const float4* pi = reinterpret_cast<const float4*>(g + m*64 + h*16);
  const float4* pj = reinterpret_cast<const float4*>(g + (btbase + j)*64 + h*16);
  float dot = 0.f;
#pragma unroll
  for (int q = 0; q < 4; ++q) {
    float4 a = pi[q], b = pj[q];
    dot = fmaf(a.x, b.x, dot); dot = fmaf(a.y, b.y, dot);
    dot = fmaf(a.z, b.z, dot); dot = fmaf(a.w, b.w, dot);
  }
  float e = s[m*4 + h] + s[(btbase + j)*4 + h] - 2.f*dot;
  float w = valid ? __expf(-e) : 0.f;
  float di = deg[m*4 + h];
  float dj = valid ? deg[(btbase + j)*4 + h] : 0.f;
  float dm = di * dj;
  float inv = (dm > 0.f) ? rsqrtf(dm) : 0.f;
  uw[m*64 + k*4 + h] = w * inv;
}

// ---- Kernel E: d_w[b,t,n,k,h] = wd_k / sum_k wd_k, wd = exp(-<a8[t,j], b8[t+1,n]>)
__global__ void __launch_bounds__(256) k_dw(
    const float* __restrict__ a8, const float* __restrict__ b8,
    const int* __restrict__ nn, float* __restrict__ dw) {
  const int t0 = blockIdx.x * blockDim.x + threadIdx.x;
  if (t0 >= NE2) return;
  const int h = t0 & 3;
  const int rest = t0 >> 2;
  const int n = rest % NNODE;
  const int q = rest / NNODE;       // 0..13
  const int b = q / 7, t = q % 7;
  const float4* pb = reinterpret_cast<const float4*>(b8 + ((size_t)((b*TT + t + 1)*NNODE + n))*32 + h*8);
  float4 b0 = pb[0], b1 = pb[1];
  float bv[8] = {b0.x, b0.y, b0.z, b0.w, b1.x, b1.y, b1.z, b1.w};
  const int nbase = n*KK1;
  const int abase = (b*TT + t)*NNODE;
  float wk[17];
  float indeg = 0.f;
#pragma unroll
  for (int k = 0; k < KK1; ++k) {
    int jr = nn[nbase + k];
    bool valid = jr >= 0;
    int j = valid ? jr : 0;
    const float4* pa = reinterpret_cast<const float4*>(a8 + ((size_t)(abase + j))*32 + h*8);
    float4 a0 = pa[0], a1 = pa[1];
    float dot = 0.f;
    dot = fmaf(a0.x, bv[0], dot); dot = fmaf(a0.y, bv[1], dot);
    dot = fmaf(a0.z, bv[2], dot); dot = fmaf(a0.w, bv[3], dot);
    dot = fmaf(a1.x, bv[4], dot); dot = fmaf(a1.y, bv[5], dot);
    dot = fmaf(a1.z, bv[6], dot); dot = fmaf(a1.w, bv[7], dot);
    float w = valid ? __expf(-dot) : 0.f;
    wk[k] = w;
    indeg += w;
  }
  float inv = (indeg > 0.f) ? (1.0f / indeg) : 0.f;
  float* o = dw + ((size_t)(b*7 + t)*NNODE + n)*68;
#pragma unroll
  for (int k = 0; k < KK1; ++k) o[k*4 + h] = wk[k] * inv;
}

extern "C" void kernel_launch(void* const* d_in, const int* in_sizes, int n_in,
                              void* d_out, int out_size, void* d_ws, size_t ws_size,
                              hipStream_t stream) {
  const float* feat = (const float*)d_in[0];
  const int*   nn   = (const int*)d_in[1];
  const float* q1   = (const float*)d_in[2];
  const float* q2   = (const float*)d_in[3];
  const float* mm   = (const float*)d_in[4];
  float* uw = (float*)d_out;
  float* dw = uw + (size_t)BB*TT*NNODE*16*HH;   // 5,120,000 elems

  const size_t G_BYTES = (size_t)NT*64*4;      // 20,480,000
  const size_t S_BYTES = (size_t)NT*4*4;       //  1,280,000
  const size_t NEED = G_BYTES + 2*S_BYTES;     // 23,040,000
  if (ws_size < NEED) {
    fprintf(stderr, "kernel_launch: ws_size %zu < needed %zu\n", ws_size, NEED);
    return;
  }
  float* g   = (float*)d_ws;
  float* s   = (float*)((char*)d_ws + G_BYTES);
  float* deg = (float*)((char*)d_ws + G_BYTES + S_BYTES);
  // a8/b8 reuse g's region (g is dead after k_uw)
  float* a8 = (float*)d_ws;
  float* b8 = (float*)((char*)d_ws + G_BYTES/2);

  k_prep_g<<<2048, 256, 0, stream>>>(feat, mm, g, s);
  k_deg  <<<NT/4, 256, 0, stream>>>(g, s, nn, deg);
  k_uw   <<<NT/4, 256, 0, stream>>>(g, s, nn, deg, uw);
  k_prep_q<<<2048, 256, 0, stream>>>(feat, q1, q2, a8, b8);
  k_dw   <<<(NE2 + 255)/256, 256, 0, stream>>>(a8, b8, nn, dw);
}

// Round 3
// 99.422 us; speedup vs baseline: 1.6923x; 1.6923x over previous
//
#include <hip/hip_runtime.h>
#include <cstdio>

#define BB 2
#define TT 8
#define NNODE 5000
#define KK1 17
#define HH 4
#define CC 16
#define NT (BB*TT*NNODE)          // 80000 (b,t,n) nodes
#define NE2 (BB*7*NNODE*HH)       // 280000 threads for d_w

// ---------------------------------------------------------------------------
// Fused prep (big-ws path): one feat pass -> g, s, a8, b8
// lane = (h,i): h=lane>>4, i=lane&15. Each lane: g-dot (16) + one q-dot (16).
__global__ void __launch_bounds__(256) k_prep_all(
    const float* __restrict__ feat, const float* __restrict__ mm,
    const float* __restrict__ q1, const float* __restrict__ q2,
    float* __restrict__ g, float* __restrict__ s,
    float* __restrict__ a8, float* __restrict__ b8) {
  const int lane = threadIdx.x & 63;
  const int h = lane >> 4, i = lane & 15;
  const int wid = (blockIdx.x * blockDim.x + threadIdx.x) >> 6;
  const int nw = (gridDim.x * blockDim.x) >> 6;
  float Mrow[16], Qrow[16];
  const float* qsrc = (i < 8) ? (q1 + (h*8 + i)*16) : (q2 + (h*8 + (i - 8))*16);
#pragma unroll
  for (int j = 0; j < 16; ++j) {
    Mrow[j] = mm[(h*16 + i)*16 + j];
    Qrow[j] = qsrc[j];
  }
  for (int m = wid; m < NT; m += nw) {
    const float4* fp = reinterpret_cast<const float4*>(feat + (size_t)m*64 + h*16);
    float fv[16];
#pragma unroll
    for (int q = 0; q < 4; ++q) {
      float4 v = fp[q];
      fv[q*4+0] = v.x; fv[q*4+1] = v.y; fv[q*4+2] = v.z; fv[q*4+3] = v.w;
    }
    float accG = 0.f, accQ = 0.f;
#pragma unroll
    for (int j = 0; j < 16; ++j) {
      accG = fmaf(Mrow[j], fv[j], accG);
      accQ = fmaf(Qrow[j], fv[j], accQ);
    }
    g[(size_t)m*64 + lane] = accG;
    float p = accG * accG;
    p += __shfl_xor(p, 1, 16);
    p += __shfl_xor(p, 2, 16);
    p += __shfl_xor(p, 4, 16);
    p += __shfl_xor(p, 8, 16);
    if (i == 0) s[m*4 + h] = p;
    if (i < 8) a8[(size_t)m*32 + h*8 + i] = accQ;
    else       b8[(size_t)m*32 + h*8 + (i - 8)] = accQ;
  }
}

// ---- small-ws path: separate preps -----------------------------------------
__global__ void __launch_bounds__(256) k_prep_g(
    const float* __restrict__ feat, const float* __restrict__ mm,
    float* __restrict__ g, float* __restrict__ s) {
  const int lane = threadIdx.x & 63;
  const int h = lane >> 4, i = lane & 15;
  const int wid = (blockIdx.x * blockDim.x + threadIdx.x) >> 6;
  const int nw = (gridDim.x * blockDim.x) >> 6;
  float Mrow[16];
#pragma unroll
  for (int j = 0; j < 16; ++j) Mrow[j] = mm[(h*16 + i)*16 + j];
  for (int m = wid; m < NT; m += nw) {
    const float4* fp = reinterpret_cast<const float4*>(feat + (size_t)m*64 + h*16);
    float fv[16];
#pragma unroll
    for (int q = 0; q < 4; ++q) {
      float4 v = fp[q];
      fv[q*4+0] = v.x; fv[q*4+1] = v.y; fv[q*4+2] = v.z; fv[q*4+3] = v.w;
    }
    float acc = 0.f;
#pragma unroll
    for (int j = 0; j < 16; ++j) acc = fmaf(Mrow[j], fv[j], acc);
    g[(size_t)m*64 + lane] = acc;
    float p = acc * acc;
    p += __shfl_xor(p, 1, 16);
    p += __shfl_xor(p, 2, 16);
    p += __shfl_xor(p, 4, 16);
    p += __shfl_xor(p, 8, 16);
    if (i == 0) s[m*4 + h] = p;
  }
}

__global__ void __launch_bounds__(256) k_prep_q(
    const float* __restrict__ feat, const float* __restrict__ q1, const float* __restrict__ q2,
    float* __restrict__ a8, float* __restrict__ b8) {
  const int lane = threadIdx.x & 63;
  const int h = lane >> 4, i = lane & 15;
  const int wid = (blockIdx.x * blockDim.x + threadIdx.x) >> 6;
  const int nw = (gridDim.x * blockDim.x) >> 6;
  const float* qsrc = (i < 8) ? (q1 + (h*8 + i)*16) : (q2 + (h*8 + (i - 8))*16);
  float Qrow[16];
#pragma unroll
  for (int j = 0; j < 16; ++j) Qrow[j] = qsrc[j];
  for (int m = wid; m < NT; m += nw) {
    const float4* fp = reinterpret_cast<const float4*>(feat + (size_t)m*64 + h*16);
    float fv[16];
#pragma unroll
    for (int q = 0; q < 4; ++q) {
      float4 v = fp[q];
      fv[q*4+0] = v.x; fv[q*4+1] = v.y; fv[q*4+2] = v.z; fv[q*4+3] = v.w;
    }
    float acc = 0.f;
#pragma unroll
    for (int j = 0; j < 16; ++j) acc = fmaf(Qrow[j], fv[j], acc);
    if (i < 8) a8[(size_t)m*32 + h*8 + i] = acc;
    else       b8[(size_t)m*32 + h*8 + (i - 8)] = acc;
  }
}

// ---------------------------------------------------------------------------
// k_deg: one wave per node. lane: k=lane>>2 (0..15), h=lane&3.
// Writes unnormalized w into wbuf (= u_w region of d_out) and deg.
// XCD-affine swizzle: grid 20000 = 8*2500; each XCD owns 2 (b,t) slices.
__global__ void __launch_bounds__(256) k_deg(
    const float* __restrict__ g, const float* __restrict__ s,
    const int* __restrict__ nn, float* __restrict__ deg,
    float* __restrict__ wbuf) {
  const int bid = blockIdx.x;
  const int work = ((bid & 7) * 2500) + (bid >> 3);
  const int m = work*4 + (threadIdx.x >> 6);
  const int lane = threadIdx.x & 63;
  const int k = lane >> 2, h = lane & 3;
  const int n = m % NNODE;
  const int btbase = m - n;
  int jr = nn[n*KK1 + 1 + k];
  bool valid = jr >= 0;
  int j = valid ? jr : 0;
  const float4* pi = reinterpret_cast<const float4*>(g + (size_t)m*64 + h*16);
  const float4* pj = reinterpret_cast<const float4*>(g + (size_t)(btbase + j)*64 + h*16);
  float dot = 0.f;
#pragma unroll
  for (int q = 0; q < 4; ++q) {
    float4 a = pi[q], b = pj[q];
    dot = fmaf(a.x, b.x, dot); dot = fmaf(a.y, b.y, dot);
    dot = fmaf(a.z, b.z, dot); dot = fmaf(a.w, b.w, dot);
  }
  float e = s[m*4 + h] + s[(btbase + j)*4 + h] - 2.f*dot;
  float w = valid ? __expf(-e) : 0.f;
  wbuf[(size_t)m*64 + lane] = w;     // offset k*4+h == lane
  float dsum = w;
  dsum += __shfl_xor(dsum, 4);
  dsum += __shfl_xor(dsum, 8);
  dsum += __shfl_xor(dsum, 16);
  dsum += __shfl_xor(dsum, 32);
  if (lane < 4) deg[m*4 + lane] = dsum;
}

// ---------------------------------------------------------------------------
// k_uw_inplace: normalize w in d_out by rsqrt(deg_i*deg_j). One elem/thread.
__global__ void __launch_bounds__(256) k_uw_inplace(
    const int* __restrict__ nn, const float* __restrict__ deg,
    float* __restrict__ wbuf) {
  const int idx = blockIdx.x * 256 + threadIdx.x;   // < NT*64
  const int m = idx >> 6;
  const int r = idx & 63;
  const int k = r >> 2, h = r & 3;
  const int n = m % NNODE;
  const int btbase = m - n;
  float w = wbuf[idx];
  float out = 0.f;
  if (w > 0.f) {
    int jr = nn[n*KK1 + 1 + k];
    int j = (jr >= 0) ? jr : 0;
    float di = deg[m*4 + h];
    float dj = deg[(btbase + j)*4 + h];
    float dm = di * dj;
    out = (dm > 0.f) ? w * rsqrtf(dm) : 0.f;
  }
  wbuf[idx] = out;
}

// ---------------------------------------------------------------------------
// k_dw: d_w[b,t,n,k,h] = wd_k / sum_k wd_k, wd = exp(-<a8[t,j], b8[t+1,n]>)
// Bijective 8-way swizzle over 1096-block grid (chunk = 137).
__global__ void __launch_bounds__(256) k_dw(
    const float* __restrict__ a8, const float* __restrict__ b8,
    const int* __restrict__ nn, float* __restrict__ dw) {
  const int bid = blockIdx.x;                 // 0..1095
  const int wg = (bid & 7) * 137 + (bid >> 3);
  const int t0 = wg * 256 + threadIdx.x;
  if (t0 >= NE2) return;
  const int h = t0 & 3;
  const int rest = t0 >> 2;
  const int n = rest % NNODE;
  const int q = rest / NNODE;       // 0..13
  const int b = q / 7, t = q % 7;
  const float4* pb = reinterpret_cast<const float4*>(b8 + ((size_t)((b*TT + t + 1)*NNODE + n))*32 + h*8);
  float4 b0 = pb[0], b1 = pb[1];
  const int nbase = n*KK1;
  const int abase = (b*TT + t)*NNODE;
  float wk[17];
  float indeg = 0.f;
#pragma unroll
  for (int k = 0; k < KK1; ++k) {
    int jr = nn[nbase + k];
    bool valid = jr >= 0;
    int j = valid ? jr : 0;
    const float4* pa = reinterpret_cast<const float4*>(a8 + ((size_t)(abase + j))*32 + h*8);
    float4 a0 = pa[0], a1 = pa[1];
    float dot = 0.f;
    dot = fmaf(a0.x, b0.x, dot); dot = fmaf(a0.y, b0.y, dot);
    dot = fmaf(a0.z, b0.z, dot); dot = fmaf(a0.w, b0.w, dot);
    dot = fmaf(a1.x, b1.x, dot); dot = fmaf(a1.y, b1.y, dot);
    dot = fmaf(a1.z, b1.z, dot); dot = fmaf(a1.w, b1.w, dot);
    float w = valid ? __expf(-dot) : 0.f;
    wk[k] = w;
    indeg += w;
  }
  float inv = (indeg > 0.f) ? (1.0f / indeg) : 0.f;
  float* o = dw + ((size_t)(b*7 + t)*NNODE + n)*68;
#pragma unroll
  for (int k = 0; k < KK1; ++k) o[k*4 + h] = wk[k] * inv;
}

extern "C" void kernel_launch(void* const* d_in, const int* in_sizes, int n_in,
                              void* d_out, int out_size, void* d_ws, size_t ws_size,
                              hipStream_t stream) {
  const float* feat = (const float*)d_in[0];
  const int*   nn   = (const int*)d_in[1];
  const float* q1   = (const float*)d_in[2];
  const float* q2   = (const float*)d_in[3];
  const float* mm   = (const float*)d_in[4];
  float* uw = (float*)d_out;                     // also the w staging buffer
  float* dw = uw + (size_t)BB*TT*NNODE*16*HH;    // 5,120,000 elems in

  const size_t G_BYTES  = (size_t)NT*64*4;       // 20,480,000
  const size_t S_BYTES  = (size_t)NT*4*4;        //  1,280,000
  const size_t AB_BYTES = (size_t)NT*32*4;       // 10,240,000 each
  const size_t NEED_SMALL = G_BYTES + 2*S_BYTES;              // 23.04 MB
  const size_t NEED_BIG   = G_BYTES + 2*S_BYTES + 2*AB_BYTES; // 43.52 MB

  if (ws_size >= NEED_BIG) {
    float* g   = (float*)d_ws;
    float* s   = (float*)((char*)d_ws + G_BYTES);
    float* deg = (float*)((char*)d_ws + G_BYTES + S_BYTES);
    float* a8  = (float*)((char*)d_ws + G_BYTES + 2*S_BYTES);
    float* b8  = (float*)((char*)d_ws + G_BYTES + 2*S_BYTES + AB_BYTES);
    k_prep_all<<<2048, 256, 0, stream>>>(feat, mm, q1, q2, g, s, a8, b8);
    k_deg<<<NT/4, 256, 0, stream>>>(g, s, nn, deg, uw);
    k_uw_inplace<<<NT/4, 256, 0, stream>>>(nn, deg, uw);
    k_dw<<<1096, 256, 0, stream>>>(a8, b8, nn, dw);
  } else if (ws_size >= NEED_SMALL) {
    float* g   = (float*)d_ws;
    float* s   = (float*)((char*)d_ws + G_BYTES);
    float* deg = (float*)((char*)d_ws + G_BYTES + S_BYTES);
    float* a8  = (float*)d_ws;                         // alias g (dead after k_deg)
    float* b8  = (float*)((char*)d_ws + G_BYTES/2);
    k_prep_g<<<2048, 256, 0, stream>>>(feat, mm, g, s);
    k_deg<<<NT/4, 256, 0, stream>>>(g, s, nn, deg, uw);
    k_prep_q<<<2048, 256, 0, stream>>>(feat, q1, q2, a8, b8);
    k_uw_inplace<<<NT/4, 256, 0, stream>>>(nn, deg, uw);
    k_dw<<<1096, 256, 0, stream>>>(a8, b8, nn, dw);
  } else {
    fprintf(stderr, "kernel_launch: ws_size %zu < needed %zu\n", ws_size, NEED_SMALL);
  }
}

// Round 4
// 64.063 us; speedup vs baseline: 2.6264x; 1.5519x over previous
//
#include <hip/hip_runtime.h>
#include <cstdio>

#define BB 2
#define TT 8
#define NNODE 5000
#define KK1 17
#define HH 4
#define NT (BB*TT*NNODE)          // 80000 (b,t,n) nodes
#define NE2 (BB*7*NNODE*HH)       // 280000 threads for d_w

typedef unsigned short u16;
typedef unsigned int u32;

__device__ __forceinline__ u16 f2bf(float x) {
  u32 u = __float_as_uint(x);
  u32 r = (u + 0x7fffu + ((u >> 16) & 1u)) >> 16;  // RNE
  return (u16)r;
}
__device__ __forceinline__ float bfLo(u32 w){ return __uint_as_float(w << 16); }
__device__ __forceinline__ float bfHi(u32 w){ return __uint_as_float(w & 0xffff0000u); }

// ---------------------------------------------------------------------------
// k_prep: feat -> g~ (bf16 [m][64]), a8~ (bf16 [m][32]), b8~ (bf16 [m][32]).
// XCD x owns m in [x*10000, (x+1)*10000). 2000 blocks; 10 m per wave.
__global__ void __launch_bounds__(256) k_prep(
    const float* __restrict__ feat, const float* __restrict__ mm,
    const float* __restrict__ q1, const float* __restrict__ q2,
    u16* __restrict__ g, u16* __restrict__ a8, u16* __restrict__ b8) {
  const int lane = threadIdx.x & 63;
  const int h = lane >> 4, i = lane & 15;
  const int bid = blockIdx.x;
  const int x = bid & 7;                                   // XCD
  const int local = (bid >> 3) * 4 + (threadIdx.x >> 6);   // 0..999 per XCD
  const int mbase = x * 10000 + local * 10;
  float Mrow[16], Qrow[16];
  const float* qsrc = (i < 8) ? (q1 + (h*8 + i)*16) : (q2 + (h*8 + (i - 8))*16);
#pragma unroll
  for (int j = 0; j < 16; ++j) {
    Mrow[j] = mm[(h*16 + i)*16 + j];
    Qrow[j] = qsrc[j];
  }
  for (int l = 0; l < 10; ++l) {
    const int m = mbase + l;
    const float4* fp = reinterpret_cast<const float4*>(feat + (size_t)m*64 + h*16);
    float fv[16];
#pragma unroll
    for (int q = 0; q < 4; ++q) {
      float4 v = fp[q];
      fv[q*4+0] = v.x; fv[q*4+1] = v.y; fv[q*4+2] = v.z; fv[q*4+3] = v.w;
    }
    float accG = 0.f, accQ = 0.f;
#pragma unroll
    for (int j = 0; j < 16; ++j) {
      accG = fmaf(Mrow[j], fv[j], accG);
      accQ = fmaf(Qrow[j], fv[j], accQ);
    }
    g[(size_t)m*64 + lane] = f2bf(accG);
    if (i < 8) a8[(size_t)m*32 + h*8 + i] = f2bf(accQ);
    else       b8[(size_t)m*32 + h*8 + (i - 8)] = f2bf(accQ);
  }
}

// ---------------------------------------------------------------------------
// k_deg: one wave per node. lane: k=lane>>2, h=lane&3.
// e = |g~_i - g~_j|^2 computed as si+sj-2dot from bf16 rows (self-consistent).
// Stores w~ (bf16) into wbuf (= d_w region of d_out) and deg (f32).
__global__ void __launch_bounds__(256) k_deg(
    const u16* __restrict__ g, const int* __restrict__ nn,
    float* __restrict__ deg, u16* __restrict__ wbuf) {
  const int bid = blockIdx.x;
  const int work = ((bid & 7) * 2500) + (bid >> 3);
  const int m = work*4 + (threadIdx.x >> 6);
  const int lane = threadIdx.x & 63;
  const int k = lane >> 2, h = lane & 3;
  const int n = m % NNODE;
  const int btbase = m - n;
  int jr = nn[n*KK1 + 1 + k];
  bool valid = jr >= 0;
  int j = valid ? jr : 0;
  const uint4* pi = reinterpret_cast<const uint4*>(g + (size_t)m*64 + h*16);
  const uint4* pj = reinterpret_cast<const uint4*>(g + (size_t)(btbase + j)*64 + h*16);
  uint4 A0 = pi[0], A1 = pi[1];
  uint4 B0 = pj[0], B1 = pj[1];
  u32 aw[8] = {A0.x,A0.y,A0.z,A0.w,A1.x,A1.y,A1.z,A1.w};
  u32 bw[8] = {B0.x,B0.y,B0.z,B0.w,B1.x,B1.y,B1.z,B1.w};
  float dot = 0.f, si = 0.f, sj = 0.f;
#pragma unroll
  for (int r = 0; r < 8; ++r) {
    float al = bfLo(aw[r]), ah = bfHi(aw[r]);
    float bl = bfLo(bw[r]), bh = bfHi(bw[r]);
    dot = fmaf(al, bl, dot); dot = fmaf(ah, bh, dot);
    si  = fmaf(al, al, si);  si  = fmaf(ah, ah, si);
    sj  = fmaf(bl, bl, sj);  sj  = fmaf(bh, bh, sj);
  }
  float e = si + sj - 2.f*dot;
  float w = valid ? __expf(-e) : 0.f;
  wbuf[(size_t)m*64 + lane] = f2bf(w);
  float dsum = w;
  dsum += __shfl_xor(dsum, 4);
  dsum += __shfl_xor(dsum, 8);
  dsum += __shfl_xor(dsum, 16);
  dsum += __shfl_xor(dsum, 32);
  if (lane < 4) deg[m*4 + lane] = dsum;
}

// ---------------------------------------------------------------------------
// k_uw: normalize. 4 elems/thread (same m,k; h=0..3). Reads w~ (uint2),
// deg_i/deg_j (float4), writes float4 to u_w. Grid 5000 = 8*625.
__global__ void __launch_bounds__(256) k_uw(
    const u16* __restrict__ wbuf, const int* __restrict__ nn,
    const float* __restrict__ deg, float* __restrict__ uw) {
  const int bid = blockIdx.x;
  const int wg = ((bid & 7) * 625) + (bid >> 3);
  const int idx4 = (wg * 256 + threadIdx.x) * 4;
  const int m = idx4 >> 6;
  const int r = idx4 & 63;
  const int k = r >> 2;
  const int n = m % NNODE;
  const int btbase = m - n;
  uint2 wv = *reinterpret_cast<const uint2*>(wbuf + idx4);
  float w0 = bfLo(wv.x), w1 = bfHi(wv.x), w2 = bfLo(wv.y), w3 = bfHi(wv.y);
  float4 out = {0.f, 0.f, 0.f, 0.f};
  int jr = nn[n*KK1 + 1 + k];
  if (jr >= 0) {
    float4 di = *reinterpret_cast<const float4*>(deg + (size_t)m*4);
    float4 dj = *reinterpret_cast<const float4*>(deg + (size_t)(btbase + jr)*4);
    float m0 = di.x*dj.x, m1 = di.y*dj.y, m2 = di.z*dj.z, m3 = di.w*dj.w;
    out.x = (w0 > 0.f && m0 > 0.f) ? w0 * rsqrtf(m0) : 0.f;
    out.y = (w1 > 0.f && m1 > 0.f) ? w1 * rsqrtf(m1) : 0.f;
    out.z = (w2 > 0.f && m2 > 0.f) ? w2 * rsqrtf(m2) : 0.f;
    out.w = (w3 > 0.f && m3 > 0.f) ? w3 * rsqrtf(m3) : 0.f;
  }
  *reinterpret_cast<float4*>(uw + idx4) = out;
}

// ---------------------------------------------------------------------------
// k_dw: d_w[b,t,n,k,h] = wd_k / sum wd_k, wd = exp(-<a8~[t,j], b8~[t+1,n]>).
// bf16 rows: one uint4 (16B) per neighbor. Grid 1096 = 8*137 (bijective).
__global__ void __launch_bounds__(256) k_dw(
    const u16* __restrict__ a8, const u16* __restrict__ b8,
    const int* __restrict__ nn, float* __restrict__ dw) {
  const int bid = blockIdx.x;
  const int wg = (bid & 7) * 137 + (bid >> 3);
  const int t0 = wg * 256 + threadIdx.x;
  if (t0 >= NE2) return;
  const int h = t0 & 3;
  const int rest = t0 >> 2;
  const int n = rest % NNODE;
  const int q = rest / NNODE;       // 0..13
  const int b = q / 7, t = q % 7;
  uint4 Bv = *reinterpret_cast<const uint4*>(b8 + ((size_t)((b*TT + t + 1)*NNODE + n))*32 + h*8);
  float bv[8] = {bfLo(Bv.x), bfHi(Bv.x), bfLo(Bv.y), bfHi(Bv.y),
                 bfLo(Bv.z), bfHi(Bv.z), bfLo(Bv.w), bfHi(Bv.w)};
  const int nbase = n*KK1;
  const int abase = (b*TT + t)*NNODE;
  float wk[17];
  float indeg = 0.f;
#pragma unroll
  for (int k = 0; k < KK1; ++k) {
    int jr = nn[nbase + k];
    bool valid = jr >= 0;
    int j = valid ? jr : 0;
    uint4 Av = *reinterpret_cast<const uint4*>(a8 + ((size_t)(abase + j))*32 + h*8);
    float dot = 0.f;
    dot = fmaf(bfLo(Av.x), bv[0], dot); dot = fmaf(bfHi(Av.x), bv[1], dot);
    dot = fmaf(bfLo(Av.y), bv[2], dot); dot = fmaf(bfHi(Av.y), bv[3], dot);
    dot = fmaf(bfLo(Av.z), bv[4], dot); dot = fmaf(bfHi(Av.z), bv[5], dot);
    dot = fmaf(bfLo(Av.w), bv[6], dot); dot = fmaf(bfHi(Av.w), bv[7], dot);
    float w = valid ? __expf(-dot) : 0.f;
    wk[k] = w;
    indeg += w;
  }
  float inv = (indeg > 0.f) ? (1.0f / indeg) : 0.f;
  float* o = dw + ((size_t)(b*7 + t)*NNODE + n)*68;
#pragma unroll
  for (int k = 0; k < KK1; ++k) o[k*4 + h] = wk[k] * inv;
}

extern "C" void kernel_launch(void* const* d_in, const int* in_sizes, int n_in,
                              void* d_out, int out_size, void* d_ws, size_t ws_size,
                              hipStream_t stream) {
  const float* feat = (const float*)d_in[0];
  const int*   nn   = (const int*)d_in[1];
  const float* q1   = (const float*)d_in[2];
  const float* q2   = (const float*)d_in[3];
  const float* mm   = (const float*)d_in[4];
  float* uw = (float*)d_out;
  float* dw = uw + (size_t)NT*64;                 // 5,120,000 elems in
  u16*   wstage = (u16*)dw;                       // w~ staged in d_w region (dead until k_dw)

  const size_t G_BYTES  = (size_t)NT*64*2;        // 10,240,000
  const size_t A_BYTES  = (size_t)NT*32*2;        //  5,120,000
  const size_t DEG_BYTES= (size_t)NT*4*4;         //  1,280,000
  const size_t NEED = G_BYTES + 2*A_BYTES + DEG_BYTES;  // 21,760,000
  if (ws_size < NEED) {
    fprintf(stderr, "kernel_launch: ws_size %zu < needed %zu\n", ws_size, NEED);
    return;
  }
  u16*   g   = (u16*)d_ws;
  u16*   a8  = (u16*)((char*)d_ws + G_BYTES);
  u16*   b8  = (u16*)((char*)d_ws + G_BYTES + A_BYTES);
  float* deg = (float*)((char*)d_ws + G_BYTES + 2*A_BYTES);

  k_prep<<<2000, 256, 0, stream>>>(feat, mm, q1, q2, g, a8, b8);
  k_deg <<<20000, 256, 0, stream>>>(g, nn, deg, wstage);
  k_uw  <<<5000, 256, 0, stream>>>(wstage, nn, deg, uw);
  k_dw  <<<1096, 256, 0, stream>>>(a8, b8, nn, dw);
}

// Round 5
// 61.290 us; speedup vs baseline: 2.7452x; 1.0452x over previous
//
#include <hip/hip_runtime.h>
#include <cstdio>

#define BB 2
#define TT 8
#define NNODE 5000
#define KK1 17
#define HH 4
#define NT (BB*TT*NNODE)          // 80000 (b,t,n) nodes
#define NREST (BB*7*NNODE)        // 70000 (b,t<7,n) rows for d_w

typedef unsigned short u16;
typedef unsigned int u32;

__device__ __forceinline__ u16 f2bf(float x) {
  u32 u = __float_as_uint(x);
  u32 r = (u + 0x7fffu + ((u >> 16) & 1u)) >> 16;  // RNE
  return (u16)r;
}
__device__ __forceinline__ float bfLo(u32 w){ return __uint_as_float(w << 16); }
__device__ __forceinline__ float bfHi(u32 w){ return __uint_as_float(w & 0xffff0000u); }

// e = |a - b|^2 from bf16 h-slices (16 elems each), self-consistent with bf16 rows
__device__ __forceinline__ float edge_e(uint4 A0, uint4 A1, uint4 B0, uint4 B1) {
  u32 aw[8] = {A0.x,A0.y,A0.z,A0.w,A1.x,A1.y,A1.z,A1.w};
  u32 bw[8] = {B0.x,B0.y,B0.z,B0.w,B1.x,B1.y,B1.z,B1.w};
  float dot = 0.f, si = 0.f, sj = 0.f;
#pragma unroll
  for (int r = 0; r < 8; ++r) {
    float al = bfLo(aw[r]), ah = bfHi(aw[r]);
    float bl = bfLo(bw[r]), bh = bfHi(bw[r]);
    dot = fmaf(al, bl, dot); dot = fmaf(ah, bh, dot);
    si  = fmaf(al, al, si);  si  = fmaf(ah, ah, si);
    sj  = fmaf(bl, bl, sj);  sj  = fmaf(bh, bh, sj);
  }
  return si + sj - 2.f*dot;
}

// ---------------------------------------------------------------------------
// k_prep: feat -> g~ (bf16 [m][64]), a8~ (bf16 [m][32]), b8~ (bf16 [m][32]).
// XCD x owns m in [x*10000, (x+1)*10000).
__global__ void __launch_bounds__(256) k_prep(
    const float* __restrict__ feat, const float* __restrict__ mm,
    const float* __restrict__ q1, const float* __restrict__ q2,
    u16* __restrict__ g, u16* __restrict__ a8, u16* __restrict__ b8) {
  const int lane = threadIdx.x & 63;
  const int h = lane >> 4, i = lane & 15;
  const int bid = blockIdx.x;
  const int x = bid & 7;                                   // XCD
  const int local = (bid >> 3) * 4 + (threadIdx.x >> 6);   // 0..999 per XCD
  const int mbase = x * 10000 + local * 10;
  float Mrow[16], Qrow[16];
  const float* qsrc = (i < 8) ? (q1 + (h*8 + i)*16) : (q2 + (h*8 + (i - 8))*16);
#pragma unroll
  for (int j = 0; j < 16; ++j) {
    Mrow[j] = mm[(h*16 + i)*16 + j];
    Qrow[j] = qsrc[j];
  }
  for (int l = 0; l < 10; ++l) {
    const int m = mbase + l;
    const float4* fp = reinterpret_cast<const float4*>(feat + (size_t)m*64 + h*16);
    float fv[16];
#pragma unroll
    for (int q = 0; q < 4; ++q) {
      float4 v = fp[q];
      fv[q*4+0] = v.x; fv[q*4+1] = v.y; fv[q*4+2] = v.z; fv[q*4+3] = v.w;
    }
    float accG = 0.f, accQ = 0.f;
#pragma unroll
    for (int j = 0; j < 16; ++j) {
      accG = fmaf(Mrow[j], fv[j], accG);
      accQ = fmaf(Qrow[j], fv[j], accQ);
    }
    g[(size_t)m*64 + lane] = f2bf(accG);
    if (i < 8) a8[(size_t)m*32 + h*8 + i] = f2bf(accQ);
    else       b8[(size_t)m*32 + h*8 + (i - 8)] = f2bf(accQ);
  }
}

// ---------------------------------------------------------------------------
// k_deg: one wave per TWO nodes (2x MLP). lane: k=lane>>2, h=lane&3.
// Stores w~ (bf16) into wbuf (= d_w region of d_out) and deg (f32).
// Grid 10000 = 8*1250; XCD x owns m in [x*10000,(x+1)*10000).
__global__ void __launch_bounds__(256) k_deg(
    const u16* __restrict__ g, const int* __restrict__ nn,
    float* __restrict__ deg, u16* __restrict__ wbuf) {
  const int bid = blockIdx.x;
  const int work = ((bid & 7) * 1250) + (bid >> 3);
  const int p = work*4 + (threadIdx.x >> 6);     // pair id, < 40000
  const int m0 = p*2, m1 = m0 + 1;
  const int lane = threadIdx.x & 63;
  const int k = lane >> 2, h = lane & 3;
  const int n0 = m0 % NNODE, n1 = m1 % NNODE;
  const int bt0 = m0 - n0, bt1 = m1 - n1;
  int jr0 = nn[n0*KK1 + 1 + k];
  int jr1 = nn[n1*KK1 + 1 + k];
  bool v0 = jr0 >= 0, v1 = jr1 >= 0;
  int j0 = v0 ? jr0 : 0;
  int j1 = v1 ? jr1 : 0;
  const uint4* pi0 = reinterpret_cast<const uint4*>(g + (size_t)m0*64 + h*16);
  const uint4* pi1 = reinterpret_cast<const uint4*>(g + (size_t)m1*64 + h*16);
  const uint4* pj0 = reinterpret_cast<const uint4*>(g + (size_t)(bt0 + j0)*64 + h*16);
  const uint4* pj1 = reinterpret_cast<const uint4*>(g + (size_t)(bt1 + j1)*64 + h*16);
  uint4 A00 = pi0[0], A01 = pi0[1];
  uint4 A10 = pi1[0], A11 = pi1[1];
  uint4 B00 = pj0[0], B01 = pj0[1];
  uint4 B10 = pj1[0], B11 = pj1[1];
  float e0 = edge_e(A00, A01, B00, B01);
  float e1 = edge_e(A10, A11, B10, B11);
  float w0 = v0 ? __expf(-e0) : 0.f;
  float w1 = v1 ? __expf(-e1) : 0.f;
  wbuf[(size_t)m0*64 + lane] = f2bf(w0);
  wbuf[(size_t)m1*64 + lane] = f2bf(w1);
  float d0 = w0, d1 = w1;
  d0 += __shfl_xor(d0, 4);  d1 += __shfl_xor(d1, 4);
  d0 += __shfl_xor(d0, 8);  d1 += __shfl_xor(d1, 8);
  d0 += __shfl_xor(d0, 16); d1 += __shfl_xor(d1, 16);
  d0 += __shfl_xor(d0, 32); d1 += __shfl_xor(d1, 32);
  if (lane < 4) {
    deg[m0*4 + lane] = d0;
    deg[m1*4 + lane] = d1;
  }
}

// ---------------------------------------------------------------------------
// k_uw: normalize, 8 elems/thread (k0,k0+1 x h=0..3). uint4 w~ read,
// 2x float4 deg_j gather, 2x float4 store. Grid 2500 (bijective 8-way, q=312 r=4).
__global__ void __launch_bounds__(256) k_uw(
    const u16* __restrict__ wbuf, const int* __restrict__ nn,
    const float* __restrict__ deg, float* __restrict__ uw) {
  const int bid = blockIdx.x;
  const int x = bid & 7, sub = bid >> 3;
  const int wg = (x < 4 ? x*313 : 4*313 + (x-4)*312) + sub;
  const int idx8 = (wg * 256 + threadIdx.x) * 8;
  const int m = idx8 >> 6;
  const int r8 = idx8 & 63;
  const int k0 = r8 >> 2;
  const int n = m % NNODE;
  const int btb = m - n;
  uint4 wv = *reinterpret_cast<const uint4*>(wbuf + idx8);
  int jr0 = nn[n*KK1 + 1 + k0];
  int jr1 = nn[n*KK1 + 2 + k0];
  float4 di = *reinterpret_cast<const float4*>(deg + (size_t)m*4);
  float4 o0 = {0.f,0.f,0.f,0.f}, o1 = {0.f,0.f,0.f,0.f};
  if (jr0 >= 0) {
    float4 dj = *reinterpret_cast<const float4*>(deg + (size_t)(btb + jr0)*4);
    float w0 = bfLo(wv.x), w1 = bfHi(wv.x), w2 = bfLo(wv.y), w3 = bfHi(wv.y);
    float p0 = di.x*dj.x, p1 = di.y*dj.y, p2 = di.z*dj.z, p3 = di.w*dj.w;
    o0.x = (w0 > 0.f && p0 > 0.f) ? w0 * rsqrtf(p0) : 0.f;
    o0.y = (w1 > 0.f && p1 > 0.f) ? w1 * rsqrtf(p1) : 0.f;
    o0.z = (w2 > 0.f && p2 > 0.f) ? w2 * rsqrtf(p2) : 0.f;
    o0.w = (w3 > 0.f && p3 > 0.f) ? w3 * rsqrtf(p3) : 0.f;
  }
  if (jr1 >= 0) {
    float4 dj = *reinterpret_cast<const float4*>(deg + (size_t)(btb + jr1)*4);
    float w0 = bfLo(wv.z), w1 = bfHi(wv.z), w2 = bfLo(wv.w), w3 = bfHi(wv.w);
    float p0 = di.x*dj.x, p1 = di.y*dj.y, p2 = di.z*dj.z, p3 = di.w*dj.w;
    o1.x = (w0 > 0.f && p0 > 0.f) ? w0 * rsqrtf(p0) : 0.f;
    o1.y = (w1 > 0.f && p1 > 0.f) ? w1 * rsqrtf(p1) : 0.f;
    o1.z = (w2 > 0.f && p2 > 0.f) ? w2 * rsqrtf(p2) : 0.f;
    o1.w = (w3 > 0.f && p3 > 0.f) ? w3 * rsqrtf(p3) : 0.f;
  }
  *reinterpret_cast<float4*>(uw + idx8)     = o0;
  *reinterpret_cast<float4*>(uw + idx8 + 4) = o1;
}

// ---------------------------------------------------------------------------
// k_dw: d_w[rest][k*4+h] = wd_k / sum wd_k, wd = exp(-<a8~[t,j], b8~[t+1,n]>).
// Block = 64 rest rows x 4 h. LDS transpose -> contiguous float4 stores.
// Grid 1094 (bijective 8-way, q=136 r=6).
__global__ void __launch_bounds__(256) k_dw(
    const u16* __restrict__ a8, const u16* __restrict__ b8,
    const int* __restrict__ nn, float* __restrict__ dw) {
  __shared__ float lds[64*68];
  const int bid = blockIdx.x;
  const int x = bid & 7, sub = bid >> 3;
  const int wg = (x < 6 ? x*137 : 6*137 + (x-6)*136) + sub;
  const int lr = threadIdx.x >> 2;          // 0..63
  const int h  = threadIdx.x & 3;
  const int rest = wg*64 + lr;
  if (rest < NREST) {
    const int n = rest % NNODE;
    const int q2 = rest / NNODE;            // 0..13
    const int b = q2 / 7, t = q2 % 7;
    uint4 Bv = *reinterpret_cast<const uint4*>(b8 + ((size_t)((b*TT + t + 1)*NNODE + n))*32 + h*8);
    float bv[8] = {bfLo(Bv.x), bfHi(Bv.x), bfLo(Bv.y), bfHi(Bv.y),
                   bfLo(Bv.z), bfHi(Bv.z), bfLo(Bv.w), bfHi(Bv.w)};
    const int nbase = n*KK1;
    const int abase = (b*TT + t)*NNODE;
    float wk[17];
    float indeg = 0.f;
#pragma unroll
    for (int kk = 0; kk < KK1; ++kk) {
      int jr = nn[nbase + kk];
      bool valid = jr >= 0;
      int j = valid ? jr : 0;
      uint4 Av = *reinterpret_cast<const uint4*>(a8 + ((size_t)(abase + j))*32 + h*8);
      float dot = 0.f;
      dot = fmaf(bfLo(Av.x), bv[0], dot); dot = fmaf(bfHi(Av.x), bv[1], dot);
      dot = fmaf(bfLo(Av.y), bv[2], dot); dot = fmaf(bfHi(Av.y), bv[3], dot);
      dot = fmaf(bfLo(Av.z), bv[4], dot); dot = fmaf(bfHi(Av.z), bv[5], dot);
      dot = fmaf(bfLo(Av.w), bv[6], dot); dot = fmaf(bfHi(Av.w), bv[7], dot);
      float w = valid ? __expf(-dot) : 0.f;
      wk[kk] = w;
      indeg += w;
    }
    float inv = (indeg > 0.f) ? (1.0f / indeg) : 0.f;
#pragma unroll
    for (int kk = 0; kk < KK1; ++kk) lds[lr*68 + kk*4 + h] = wk[kk] * inv;
  }
  __syncthreads();
  const int rows = NREST - wg*64;                       // rows in this block
  const int nchunks = (rows >= 64 ? 64 : rows) * 17;    // float4 chunks
  float4* obase = reinterpret_cast<float4*>(dw + (size_t)wg*4352);
  for (int c = threadIdx.x; c < nchunks; c += 256) {
    const int row = c / 17;
    const int col = (c % 17) * 4;
    obase[c] = *reinterpret_cast<const float4*>(&lds[row*68 + col]);
  }
}

extern "C" void kernel_launch(void* const* d_in, const int* in_sizes, int n_in,
                              void* d_out, int out_size, void* d_ws, size_t ws_size,
                              hipStream_t stream) {
  const float* feat = (const float*)d_in[0];
  const int*   nn   = (const int*)d_in[1];
  const float* q1   = (const float*)d_in[2];
  const float* q2   = (const float*)d_in[3];
  const float* mm   = (const float*)d_in[4];
  float* uw = (float*)d_out;
  float* dw = uw + (size_t)NT*64;                 // 5,120,000 elems in
  u16*   wstage = (u16*)dw;                       // w~ staged in d_w region (dead until k_dw)

  const size_t G_BYTES  = (size_t)NT*64*2;        // 10,240,000
  const size_t A_BYTES  = (size_t)NT*32*2;        //  5,120,000
  const size_t DEG_BYTES= (size_t)NT*4*4;         //  1,280,000
  const size_t NEED = G_BYTES + 2*A_BYTES + DEG_BYTES;  // 21,760,000
  if (ws_size < NEED) {
    fprintf(stderr, "kernel_launch: ws_size %zu < needed %zu\n", ws_size, NEED);
    return;
  }
  u16*   g   = (u16*)d_ws;
  u16*   a8  = (u16*)((char*)d_ws + G_BYTES);
  u16*   b8  = (u16*)((char*)d_ws + G_BYTES + A_BYTES);
  float* deg = (float*)((char*)d_ws + G_BYTES + 2*A_BYTES);

  k_prep<<<2000, 256, 0, stream>>>(feat, mm, q1, q2, g, a8, b8);
  k_deg <<<10000, 256, 0, stream>>>(g, nn, deg, wstage);
  k_uw  <<<2500, 256, 0, stream>>>(wstage, nn, deg, uw);
  k_dw  <<<1094, 256, 0, stream>>>(a8, b8, nn, dw);
}